// Round 7
// baseline (79.799 us; speedup 1.0000x reference)
//
#include <hip/hip_runtime.h>
#include <stdint.h>

// Bit-serial conv2d closed form: term = sign(w) * ((x * |w|) >> 4)
//                                     = (x * w + A) >> 4   [arith shift, per i16 lane]
// where A = (w<0) ? 15 : 0.  x in [0,15], w in [-8,7].
// out = relu(bias + sum_{3x3,c} term).  B=4 H=32 W=32 C=64 F=128.
// Exact in i16 (per-thread |acc| <= 7*144 = 1008).
//
// Round 7: VOP3P inline asm, but ALL packed operands are VGPRs.
// Round 6's bug: `v_pk_ashrrev_i16 d, 4, v` -- asm default op_sel_hi=[1,1,1]
// makes the HIGH lane use the high half of the constant (= 0), so the high
// i16 lane was shifted by 0.  Shift amounts now live in VGPRs as 0x00040004 /
// 0x000F000F so both lanes see the right amount.

#define NWPK 36864            // 9*2*512*4 packed weight dwords (2 i16 each)
#define XOFF 36864            // dword offset of padded x in ws
#define NXPK 147968           // 4*34*34*32 padded input dwords (2 i16 each)

static __device__ __forceinline__ int pk_mad_i16(int a, int b, int c) {
    int d;
    asm("v_pk_mad_i16 %0, %1, %2, %3" : "=v"(d) : "v"(a), "v"(b), "v"(c));
    return d;
}
// d.lane = a.lane >> sh.lane  (shift amounts passed per-lane in a VGPR!)
static __device__ __forceinline__ int pk_ashr(int sh, int a) {
    int d;
    asm("v_pk_ashrrev_i16 %0, %1, %2" : "=v"(d) : "v"(sh), "v"(a));
    return d;
}
static __device__ __forceinline__ int pk_add_i16(int a, int b) {
    int d;
    asm("v_pk_add_i16 %0, %1, %2" : "=v"(d) : "v"(a), "v"(b));
    return d;
}

// blocks [0,144): weight pack (VGPR-slice layout); [144,723): pad+pack x.
// Weight dword index: ((ki*2+g)*512 + cq*128 + f)*4 + u
//   holds channels c = cq*16 + g*8 + u*2 and c+1 for filter f, position ki.
__global__ __launch_bounds__(256) void prep_all(const float* __restrict__ kern,
                                                const float* __restrict__ input,
                                                uint32_t* __restrict__ ws) {
    int bid = blockIdx.x, tid = threadIdx.x;
    if (bid < 144) {
        int t  = bid * 256 + tid;            // < 36864
        int u  = t & 3;
        int f  = (t >> 2) & 127;
        int cq = (t >> 9) & 3;
        int gk = t >> 11;                    // ki*2 + g
        int g  = gk & 1;
        int ki = gk >> 1;
        int c  = cq * 16 + g * 8 + u * 2;
        int wlo = (int)kern[(ki * 64 + c    ) * 128 + f];   // src [ki][c][f]
        int whi = (int)kern[(ki * 64 + c + 1) * 128 + f];
        ws[t] = (uint32_t)(uint16_t)(int16_t)wlo |
                ((uint32_t)(uint16_t)(int16_t)whi << 16);
    } else {
        int t = (bid - 144) * 256 + tid;     // < 147968
        if (t >= NXPK) return;
        int c2    = t & 31;
        int rest  = t >> 5;                  // b*34*34 + hp*34 + wp
        int wp    = rest % 34;
        int rest2 = rest / 34;
        int hp    = rest2 % 34;
        int b     = rest2 / 34;
        int v = 0;
        if (hp >= 1 && hp <= 32 && wp >= 1 && wp <= 32) {
            const float* p = &input[(((b * 32) + hp - 1) * 32 + (wp - 1)) * 64 + c2 * 2];
            v = (int)p[0] | ((int)p[1] << 16);
        }
        ws[XOFF + t] = (uint32_t)v;
    }
}

// 1024 blocks x 512 threads. Block = (b, h, wq): 4 output cols x 128 f.
// Thread (cq = tid>>7, f = tid&127): 16-ch x 9-pos weight slice in 18 int4
// VGPRs; 6 x-columns per (row,g) hoisted to VGPRs; 4 pixel partials; LDS reduce.
__global__ __launch_bounds__(512, 4) void conv_main(const uint32_t* __restrict__ ws,
                                                    const float* __restrict__ bias,
                                                    float* __restrict__ out) {
    const uint32_t* xpk = ws + XOFF;

    int bid = blockIdx.x;
    int wq  = bid & 7;
    int h   = (bid >> 3) & 31;
    int b   = bid >> 8;
    int tid = threadIdx.x;
    int f   = tid & 127;
    int cq  = tid >> 7;          // wave-uniform
    int w0  = wq * 4;

    __shared__ uint32_t xl[3 * 6 * 32];    // [row][col 0..5][c2]   2.25 KB
    __shared__ int prt[4 * 4 * 128];       // partial [cq][px][f]   8 KB

    // stage x-patch: 576 dwords (pre-padded global -> no bounds checks)
    #pragma unroll
    for (int pass = 0; pass < 2; ++pass) {
        int k = pass * 512 + tid;
        if (k < 576) {
            int c2  = k & 31;
            int rc  = k >> 5;
            int col = rc % 6;
            int r   = rc / 6;
            xl[k] = xpk[((b * 34 + h + r) * 34 + (w0 + col)) * 32 + c2];
        }
    }

    // weight slice -> 72 VGPRs, one coalesced pass (1 KB/wave/instr, L2-hot)
    int4 wv[18];
    const int4* wp = (const int4*)ws;
    #pragma unroll
    for (int i = 0; i < 18; ++i) wv[i] = wp[i * 512 + tid];

    __syncthreads();

    const int SH4  = 0x00040004;   // per-lane shift 4  (VGPR operand!)
    const int SH15 = 0x000F000F;   // per-lane shift 15
    int acc0 = 0, acc1 = 0, acc2 = 0, acc3 = 0;   // packed 2x i16

    #pragma unroll
    for (int row = 0; row < 3; ++row) {
        #pragma unroll
        for (int g = 0; g < 2; ++g) {
            // 6 distinct x columns for this (row, g): hoist to VGPRs once
            const uint32_t* xb = xl + (row * 6) * 32 + cq * 8 + g * 4;
            int4 xc[6];
            #pragma unroll
            for (int cidx = 0; cidx < 6; ++cidx)
                xc[cidx] = *(const int4*)(xb + cidx * 32);   // ds_read_b128 bcast
            #pragma unroll
            for (int j = 0; j < 3; ++j) {
                const int4 w4 = wv[(row * 3 + j) * 2 + g];
                #pragma unroll
                for (int u = 0; u < 4; ++u) {
                    int w2 = (&w4.x)[u];
                    int A  = pk_ashr(SH15, w2) & 0x000F000F;  // 15 per negative lane
                    acc0 = pk_add_i16(acc0, pk_ashr(SH4, pk_mad_i16((&xc[j + 0].x)[u], w2, A)));
                    acc1 = pk_add_i16(acc1, pk_ashr(SH4, pk_mad_i16((&xc[j + 1].x)[u], w2, A)));
                    acc2 = pk_add_i16(acc2, pk_ashr(SH4, pk_mad_i16((&xc[j + 2].x)[u], w2, A)));
                    acc3 = pk_add_i16(acc3, pk_ashr(SH4, pk_mad_i16((&xc[j + 3].x)[u], w2, A)));
                }
            }
        }
    }

    // per-thread horizontal add (2 channel halves), stash partial
    prt[(cq * 4 + 0) * 128 + f] = (int)(short)(acc0 & 0xffff) + (acc0 >> 16);
    prt[(cq * 4 + 1) * 128 + f] = (int)(short)(acc1 & 0xffff) + (acc1 >> 16);
    prt[(cq * 4 + 2) * 128 + f] = (int)(short)(acc2 & 0xffff) + (acc2 >> 16);
    prt[(cq * 4 + 3) * 128 + f] = (int)(short)(acc3 & 0xffff) + (acc3 >> 16);
    __syncthreads();

    // reduce 4 c-quarters, bias, relu, store: 512 outputs / 512 threads
    {
        int ff = tid & 127;
        int px = tid >> 7;
        int v = prt[(0 * 4 + px) * 128 + ff] + prt[(1 * 4 + px) * 128 + ff] +
                prt[(2 * 4 + px) * 128 + ff] + prt[(3 * 4 + px) * 128 + ff] +
                (int)bias[ff];
        out[((b * 32 + h) * 32 + w0 + px) * 128 + ff] = (float)(v < 0 ? 0 : v);
    }
}

extern "C" void kernel_launch(void* const* d_in, const int* in_sizes, int n_in,
                              void* d_out, int out_size, void* d_ws, size_t ws_size,
                              hipStream_t stream) {
    const float* input  = (const float*)d_in[0];   // [4,32,32,64]
    const float* kernel = (const float*)d_in[1];   // [3,3,64,128]
    const float* bias   = (const float*)d_in[2];   // [128]
    // d_in[3] = bits (==4, baked into the closed form)

    uint32_t* ws = (uint32_t*)d_ws;                // 36864 + 147968 dwords used

    prep_all<<<144 + 579, 256, 0, stream>>>(kernel, input, ws);
    conv_main<<<1024, 512, 0, stream>>>(ws, bias, (float*)d_out);
}

// Round 8
// 79.665 us; speedup vs baseline: 1.0017x; 1.0017x over previous
//
#include <hip/hip_runtime.h>
#include <stdint.h>

// Bit-serial conv2d closed form: term = sign(w) * ((x * |w|) >> 4)
//                                     = (x * w + A) >> 4   [arith shift, per i16 lane]
// where A = (w<0) ? 15 : 0.  x in [0,15], w in [-8,7].
// out = relu(bias + sum_{3x3,c} term).  B=4 H=32 W=32 C=64 F=128.
// Exact in i16 (per-thread |acc| <= 7*72 = 504).
//
// Round 8: register-pressure fix.  Thread = (ce in [0,8), f64 in [0,64)):
// 8-channel x 9-position weight slice = 9 int4 = 36 VGPRs (was 72).  Live set
// ~85 regs, far under the launch_bounds(512,4) cap of 128 -> spilling
// impossible (rounds 4-7 were pinned at ~34us consistent with weight-reg
// spill-to-scratch at the 128-reg cliff).

#define XOFF 36864            // dword offset of padded x in ws
#define NXPK 147968           // 4*34*34*32 padded input dwords (2 i16 each)

static __device__ __forceinline__ int pk_mad_i16(int a, int b, int c) {
    int d;
    asm("v_pk_mad_i16 %0, %1, %2, %3" : "=v"(d) : "v"(a), "v"(b), "v"(c));
    return d;
}
// d.lane = a.lane >> sh.lane  (shift amounts per-lane in a VGPR -- VOP3P
// inline constants splat only the low 16 bits into the high lane!)
static __device__ __forceinline__ int pk_ashr(int sh, int a) {
    int d;
    asm("v_pk_ashrrev_i16 %0, %1, %2" : "=v"(d) : "v"(sh), "v"(a));
    return d;
}
static __device__ __forceinline__ int pk_add_i16(int a, int b) {
    int d;
    asm("v_pk_add_i16 %0, %1, %2" : "=v"(d) : "v"(a), "v"(b));
    return d;
}

// blocks [0,144): weight pack; [144,723): pad+pack x.
// Weight dword index: ((ki*2+fh)*512 + ce*64 + f64)*4 + u
//   holds channels c = ce*8 + u*2, c+1 for filter fh*64+f64, position ki.
// -> consumer thread tid = ce*64+f64 of f-half fh loads int4 at
//    int4-index (ki*2+fh)*512 + tid : coalesced.
__global__ __launch_bounds__(256) void prep_all(const float* __restrict__ kern,
                                                const float* __restrict__ input,
                                                uint32_t* __restrict__ ws) {
    int bid = blockIdx.x, tid = threadIdx.x;
    if (bid < 144) {
        int t    = bid * 256 + tid;          // < 36864
        int u    = t & 3;
        int rest = t >> 2;
        int f64  = rest & 63;
        int ce   = (rest >> 6) & 7;
        int kifh = rest >> 9;                // ki*2 + fh
        int fh   = kifh & 1;
        int ki   = kifh >> 1;
        int c    = ce * 8 + u * 2;
        int f    = fh * 64 + f64;
        int wlo = (int)kern[(ki * 64 + c    ) * 128 + f];   // src [ki][c][f]
        int whi = (int)kern[(ki * 64 + c + 1) * 128 + f];
        ws[t] = (uint32_t)(uint16_t)(int16_t)wlo |
                ((uint32_t)(uint16_t)(int16_t)whi << 16);
    } else {
        int t = (bid - 144) * 256 + tid;     // < 147968
        if (t >= NXPK) return;
        int c2    = t & 31;
        int rest  = t >> 5;                  // b*34*34 + hp*34 + wp
        int wp    = rest % 34;
        int rest2 = rest / 34;
        int hp    = rest2 % 34;
        int b     = rest2 / 34;
        int v = 0;
        if (hp >= 1 && hp <= 32 && wp >= 1 && wp <= 32) {
            const float* p = &input[(((b * 32) + hp - 1) * 32 + (wp - 1)) * 64 + c2 * 2];
            v = (int)p[0] | ((int)p[1] << 16);
        }
        ws[XOFF + t] = (uint32_t)v;
    }
}

// 2048 blocks x 512 threads. Block = (b, h, wq, fh): 4 output cols x 64 f.
// Thread (ce = tid>>6 [wave-uniform], f64 = tid&63): 8-ch x 9-pos weight
// slice in 9 int4 VGPRs; 6 x-columns per row hoisted; 4 px partials; LDS reduce.
__global__ __launch_bounds__(512, 4) void conv_main(const uint32_t* __restrict__ ws,
                                                    const float* __restrict__ bias,
                                                    float* __restrict__ out) {
    const uint32_t* xpk = ws + XOFF;

    int bid = blockIdx.x;
    int fh  = bid & 1;
    int wq  = (bid >> 1) & 7;
    int h   = (bid >> 4) & 31;
    int b   = bid >> 9;
    int tid = threadIdx.x;
    int f64 = tid & 63;
    int ce  = tid >> 6;          // wave-uniform
    int w0  = wq * 4;

    __shared__ uint32_t xl[3 * 6 * 32];    // [row][col 0..5][c2]   2.25 KB
    __shared__ int prt[8 * 4 * 64];        // partial [ce][px][f64] 8 KB

    // stage x-patch: 576 dwords (pre-padded global -> no bounds checks)
    #pragma unroll
    for (int pass = 0; pass < 2; ++pass) {
        int k = pass * 512 + tid;
        if (k < 576) {
            int c2  = k & 31;
            int rc  = k >> 5;
            int col = rc % 6;
            int r   = rc / 6;
            xl[k] = xpk[((b * 34 + h + r) * 34 + (w0 + col)) * 32 + c2];
        }
    }

    // weight slice -> 36 VGPRs, one coalesced pass (1 KB/wave/instr, L2-hot)
    int4 wv[9];
    const int4* wp4 = (const int4*)ws;
    #pragma unroll
    for (int ki = 0; ki < 9; ++ki) wv[ki] = wp4[(ki * 2 + fh) * 512 + tid];

    __syncthreads();

    const int SH4  = 0x00040004;   // per-lane shift 4  (VGPR operand)
    const int SH15 = 0x000F000F;   // per-lane shift 15
    int acc0 = 0, acc1 = 0, acc2 = 0, acc3 = 0;   // packed 2x i16

    #pragma unroll
    for (int row = 0; row < 3; ++row) {
        // 6 distinct x columns for this row (8 ch = one int4 each)
        const uint32_t* xb = xl + (row * 6) * 32 + ce * 4;
        int4 xc[6];
        #pragma unroll
        for (int cidx = 0; cidx < 6; ++cidx)
            xc[cidx] = *(const int4*)(xb + cidx * 32);   // ds_read_b128 bcast
        #pragma unroll
        for (int j = 0; j < 3; ++j) {
            const int4 w4 = wv[row * 3 + j];
            #pragma unroll
            for (int u = 0; u < 4; ++u) {
                int w2 = (&w4.x)[u];
                int A  = pk_ashr(SH15, w2) & 0x000F000F;  // 15 per negative lane
                acc0 = pk_add_i16(acc0, pk_ashr(SH4, pk_mad_i16((&xc[j + 0].x)[u], w2, A)));
                acc1 = pk_add_i16(acc1, pk_ashr(SH4, pk_mad_i16((&xc[j + 1].x)[u], w2, A)));
                acc2 = pk_add_i16(acc2, pk_ashr(SH4, pk_mad_i16((&xc[j + 2].x)[u], w2, A)));
                acc3 = pk_add_i16(acc3, pk_ashr(SH4, pk_mad_i16((&xc[j + 3].x)[u], w2, A)));
            }
        }
    }

    // per-thread horizontal add (2 channel halves), stash partial
    prt[(ce * 4 + 0) * 64 + f64] = (int)(short)(acc0 & 0xffff) + (acc0 >> 16);
    prt[(ce * 4 + 1) * 64 + f64] = (int)(short)(acc1 & 0xffff) + (acc1 >> 16);
    prt[(ce * 4 + 2) * 64 + f64] = (int)(short)(acc2 & 0xffff) + (acc2 >> 16);
    prt[(ce * 4 + 3) * 64 + f64] = (int)(short)(acc3 & 0xffff) + (acc3 >> 16);
    __syncthreads();

    // reduce 8 c-eighths, bias, relu, store: 256 outputs, threads [0,256)
    if (tid < 256) {
        int ff = tid & 63;
        int px = tid >> 6;
        int v = 0;
        #pragma unroll
        for (int e = 0; e < 8; ++e) v += prt[(e * 4 + px) * 64 + ff];
        v += (int)bias[fh * 64 + ff];
        out[((b * 32 + h) * 32 + w0 + px) * 128 + fh * 64 + ff] =
            (float)(v < 0 ? 0 : v);
    }
}

extern "C" void kernel_launch(void* const* d_in, const int* in_sizes, int n_in,
                              void* d_out, int out_size, void* d_ws, size_t ws_size,
                              hipStream_t stream) {
    const float* input  = (const float*)d_in[0];   // [4,32,32,64]
    const float* kernel = (const float*)d_in[1];   // [3,3,64,128]
    const float* bias   = (const float*)d_in[2];   // [128]
    // d_in[3] = bits (==4, baked into the closed form)

    uint32_t* ws = (uint32_t*)d_ws;                // 36864 + 147968 dwords used

    prep_all<<<144 + 579, 256, 0, stream>>>(kernel, input, ws);
    conv_main<<<2048, 512, 0, stream>>>(ws, bias, (float*)d_out);
}